// Round 2
// baseline (1063.400 us; speedup 1.0000x reference)
//
#include <hip/hip_runtime.h>

#define Bn  32
#define Nn  12000
#define Tn  20000
#define N1n 4000
#define N2n 1000
#define NXn 5000   // N1+N2

// ---------------- workspace layout (floats) ----------------
// PT   [12000][3][32]  batch-modified point coords, b-fastest   1,152,000
// DYZT [20000][32]     dyT, later reused as dzT                   640,000
// CY   [4000][32]      coeffy, j-major b-fastest                  128,000
// CZ   [5000][32]      coeffz, j-major b-fastest                  160,000
// VOL/VOLC/A/FY/FZ scalars
#define OFF_PT    0
#define OFF_DYZT  1152000
#define OFF_CY    1792000
#define OFF_CZ    1920000
#define OFF_VOL   2080000
#define OFF_VOLC  2080032
#define OFF_A     2080064
#define OFF_FY    2080096
#define OFF_FZ    2080128

// ---------------- K0: build PT[i][c][b] + vol_const (fused) ----------------
#define NPREP 4500   // 4500*256 == Nn*96 exactly
__global__ void k_init(const float* __restrict__ x, const float* __restrict__ y,
                       const float* __restrict__ pz, const int* __restrict__ tri,
                       float* __restrict__ PT, float* __restrict__ volc)
{
  if (blockIdx.x < NPREP) {
    int idx = blockIdx.x * 256 + threadIdx.x;
    int b  = idx & 31;
    int rc = idx >> 5;           // i*3 + c
    int i  = rc / 3;
    int c  = rc - i * 3;
    float v;
    if (i < N1n) {
      v = x[(size_t)b * (N1n * 3) + i * 3 + c];
    } else if (i < NXn) {
      v = (c == 1) ? pz[3 * i + 1]
                   : y[(size_t)b * (N2n * 2) + (i - N1n) * 2 + (c >> 1)];
    } else {
      v = pz[3 * i + c];
    }
    PT[idx] = v;
    return;
  }
  // vol_const part
  int t = (blockIdx.x - NPREP) * 256 + threadIdx.x;
  float acc = 0.f;
  if (t < Tn) {
    int i0 = tri[3 * t], i1 = tri[3 * t + 1], i2 = tri[3 * t + 2];
    float q0x = pz[3 * i0], q0y = pz[3 * i0 + 1], q0z = pz[3 * i0 + 2];
    float q1x = pz[3 * i1], q1y = pz[3 * i1 + 1], q1z = pz[3 * i1 + 2];
    float q2x = pz[3 * i2], q2y = pz[3 * i2 + 1], q2z = pz[3 * i2 + 2];
    float dy0 = ((q0x - q1x) * (q2z - q1z) - (q0z - q1z) * (q2x - q1x)) * (1.0f / 6.0f);
    acc = (q0y + q1y + q2y) * dy0;
  }
  __shared__ float red[256];
  red[threadIdx.x] = acc;
  __syncthreads();
  for (int off = 128; off; off >>= 1) {
    if (threadIdx.x < off) red[threadIdx.x] += red[threadIdx.x + off];
    __syncthreads();
  }
  if (threadIdx.x == 0) atomicAdd(volc, red[0]);
}

// ---------------- K1: dy (t-major [t][b]) + per-batch volume ----------------
__global__ void k_dy_vol(const float* __restrict__ PT, const int* __restrict__ tri,
                         float* __restrict__ dyT, float* __restrict__ vol)
{
  const int tid = threadIdx.x;
  const int b  = tid & 31;
  const int tl = tid >> 5;           // 0..7
  float accV = 0.f;
  for (int t = blockIdx.x * 8 + tl; t < Tn; t += gridDim.x * 8) {
    const int i0 = tri[3 * t], i1 = tri[3 * t + 1], i2 = tri[3 * t + 2];
    const float* P0 = PT + (size_t)i0 * 96;
    const float* P1 = PT + (size_t)i1 * 96;
    const float* P2 = PT + (size_t)i2 * 96;
    float p0x = P0[b], p0y = P0[32 + b], p0z = P0[64 + b];
    float p1x = P1[b], p1y = P1[32 + b], p1z = P1[64 + b];
    float p2x = P2[b], p2y = P2[32 + b], p2z = P2[64 + b];
    float dy = ((p0x - p1x) * (p2z - p1z) - (p0z - p1z) * (p2x - p1x)) * (1.0f / 6.0f);
    dyT[(size_t)t * 32 + b] = dy;
    accV += (p0y + p1y + p2y) * dy;
  }
  __shared__ float red[256];
  red[tid] = accV;
  __syncthreads();
  if (tl == 0) {
    float s = accV;
    #pragma unroll
    for (int q = 1; q < 8; ++q) s += red[q * 32 + b];
    atomicAdd(&vol[b], s);
  }
}

// ---------------- K3: dz (t-major) with corrected y ----------------
__global__ void k_dz(const float* __restrict__ PT, const int* __restrict__ tri,
                     const float* __restrict__ cy, const float* __restrict__ fy,
                     float* __restrict__ dzT)
{
  const int tid = threadIdx.x;
  const int b  = tid & 31;
  const int tl = tid >> 5;
  const float fyb = fy[b];
  for (int t = blockIdx.x * 8 + tl; t < Tn; t += gridDim.x * 8) {
    const int i0 = tri[3 * t], i1 = tri[3 * t + 1], i2 = tri[3 * t + 2];
    const float* P0 = PT + (size_t)i0 * 96;
    const float* P1 = PT + (size_t)i1 * 96;
    const float* P2 = PT + (size_t)i2 * 96;
    float p0x = P0[b], p0y = P0[32 + b];
    float p1x = P1[b], p1y = P1[32 + b];
    float p2x = P2[b], p2y = P2[32 + b];
    if (i0 < N1n) p0y += cy[(size_t)i0 * 32 + b] * fyb;
    if (i1 < N1n) p1y += cy[(size_t)i1 * 32 + b] * fyb;
    if (i2 < N1n) p2y += cy[(size_t)i2 * 32 + b] * fyb;
    float dz = ((p0x - p2x) * (p1y - p2y) - (p0y - p2y) * (p1x - p2x)) * (1.0f / 6.0f);
    dzT[(size_t)t * 32 + b] = dz;
  }
}

// ---------------- split-K GEMM: C[j][b] += sum_t A[t][b] * V[j][t] ----------------
// 256 threads = 4 waves; wave = (kh in {0,1}) x (b in 0..31); wave owns 32 j's.
// A[k][b] kept in registers (coalesced global loads, no LDS).
// V staged row-major [128][32] in LDS, consumed as wave-wide float4 BROADCASTS
// (1 LDS txn per 8 FMA instr -> LDS pipe far below 128 B/clk ceiling).
#define GKT 32      // k per tile
#define GJT 128     // j per block
#define GKC 800     // k per block (25 tiles); 25 * 800 == 20000 exact
#define SVP 36      // padded row stride (words); keeps 16B alignment

__global__ __launch_bounds__(256, 4)
void k_gemm(const float* __restrict__ A,   // [Tn][32] t-major
            const float* __restrict__ V,   // [NJ][Tn]
            float* __restrict__ C,         // [NJ][32] j-major
            int NJ)
{
  __shared__ float sV[GJT * SVP];          // 18.4 KB
  const int tid  = threadIdx.x;
  const int lane = tid & 63;
  const int b    = lane & 31;
  const int kh   = lane >> 5;              // 0/1: which 16-k half
  const int jw0  = (tid >> 6) * 32;        // wave's j base within block tile
  const int jb   = blockIdx.y * GJT;
  const int t0   = blockIdx.x * GKC;
  const int srow = tid >> 1;               // 0..127 staging row
  const int scol = (tid & 1) * 16;         // 0 or 16

  float acc[32];
  #pragma unroll
  for (int j = 0; j < 32; ++j) acc[j] = 0.f;

  for (int it = 0; it < GKC / GKT; ++it) {
    const int tk = t0 + it * GKT;
    __syncthreads();
    // stage V rows (coalesced 64B per thread, row-major, no transpose)
    {
      const int jg = jb + srow;
      float4 v0, v1, v2, v3;
      if (jg < NJ) {
        const float* src = V + (size_t)jg * Tn + tk + scol;
        v0 = *(const float4*)(src);
        v1 = *(const float4*)(src + 4);
        v2 = *(const float4*)(src + 8);
        v3 = *(const float4*)(src + 12);
      } else {
        v0 = v1 = v2 = v3 = make_float4(0.f, 0.f, 0.f, 0.f);
      }
      float* dst = sV + srow * SVP + scol;
      *(float4*)(dst)      = v0;
      *(float4*)(dst + 4)  = v1;
      *(float4*)(dst + 8)  = v2;
      *(float4*)(dst + 12) = v3;
    }
    // A fragment: 16 k-values for (my b, my k-half), coalesced b32 loads
    float ar[16];
    {
      const float* ap = A + (size_t)(tk + kh * 16) * 32 + b;
      #pragma unroll
      for (int k = 0; k < 16; ++k) ar[k] = ap[k * 32];
    }
    __syncthreads();
    // compute: 32 j x 16 FMA, V via wave-wide broadcasts
    #pragma unroll
    for (int j = 0; j < 32; ++j) {
      const float* vp = sV + (jw0 + j) * SVP + kh * 16;
      float4 v0 = *(const float4*)(vp);
      float4 v1 = *(const float4*)(vp + 4);
      float4 v2 = *(const float4*)(vp + 8);
      float4 v3 = *(const float4*)(vp + 12);
      float s = acc[j];
      s += ar[0]  * v0.x; s += ar[1]  * v0.y; s += ar[2]  * v0.z; s += ar[3]  * v0.w;
      s += ar[4]  * v1.x; s += ar[5]  * v1.y; s += ar[6]  * v1.z; s += ar[7]  * v1.w;
      s += ar[8]  * v2.x; s += ar[9]  * v2.y; s += ar[10] * v2.z; s += ar[11] * v2.w;
      s += ar[12] * v3.x; s += ar[13] * v3.y; s += ar[14] * v3.z; s += ar[15] * v3.w;
      acc[j] = s;
    }
  }
  // merge the two k-halves, then each half writes its own 16 j's (static idx)
  #pragma unroll
  for (int j = 0; j < 32; ++j) acc[j] += __shfl_xor(acc[j], 32, 64);
  if (kh == 0) {
    #pragma unroll
    for (int j = 0; j < 16; ++j) {
      int jg = jb + jw0 + j;
      if (jg < NJ) atomicAdd(&C[(size_t)jg * 32 + b], acc[j]);
    }
  } else {
    #pragma unroll
    for (int j = 0; j < 16; ++j) {
      int jg = jb + jw0 + 16 + j;
      if (jg < NJ) atomicAdd(&C[(size_t)jg * 32 + b], acc[16 + j]);
    }
  }
}

// ---------------- K2/K4: s[b] = sum_j coeff[j][b]^2 ; factor = a / s ----------------
// one block, 1024 threads, fully coalesced ([j][b] layout)
__global__ void k_factor(const float* __restrict__ coeff, int NJ,
    const float* __restrict__ vol, const float* __restrict__ volc,
    float* __restrict__ aArr, float* __restrict__ factor, int computeA)
{
  const int tid = threadIdx.x;
  const int b = tid & 31, g = tid >> 5;    // 32 j-groups
  float s = 0.f;
  for (int j = g; j < NJ; j += 32) {
    float v = coeff[(size_t)j * 32 + b];
    s += v * v;
  }
  __shared__ float red[1024];
  red[tid] = s;
  __syncthreads();
  if (tid < 32) {
    float t = red[tid];
    #pragma unroll
    for (int q = 1; q < 32; ++q) t += red[q * 32 + tid];
    float a;
    if (computeA) { a = 0.5f * (volc[0] - vol[tid]); aArr[tid] = a; }
    else          { a = aArr[tid]; }
    factor[tid] = a / t;
  }
}

// ---------------- K5: assemble outputs ----------------
__global__ void k_out(const float* __restrict__ x, const float* __restrict__ y,
    const float* __restrict__ cy, const float* __restrict__ cz,
    const float* __restrict__ fy, const float* __restrict__ fz,
    float* __restrict__ out)
{
  int idx = blockIdx.x * blockDim.x + threadIdx.x;
  if (idx >= 448000) return;
  if (idx < 384000) {
    int b = idx / 12000;
    int r = idx - b * 12000;
    int i = r / 3, c = r - i * 3;
    float v = x[(size_t)b * 12000 + r];
    if (c == 1)      v += cy[(size_t)i * 32 + b] * fy[b];
    else if (c == 2) v += cz[(size_t)i * 32 + b] * fz[b];
    out[idx] = v;
  } else {
    int k = idx - 384000;
    int b = k / 2000;
    int r = k - b * 2000;
    int i = r >> 1, c = r & 1;
    float v = y[(size_t)b * 2000 + r];
    if (c) v += cz[(size_t)(N1n + i) * 32 + b] * fz[b];
    out[idx] = v;
  }
}

// ---------------- launch ----------------
extern "C" void kernel_launch(void* const* d_in, const int* in_sizes, int n_in,
                              void* d_out, int out_size, void* d_ws, size_t ws_size,
                              hipStream_t stream)
{
  const float* x   = (const float*)d_in[0];
  const float* y   = (const float*)d_in[1];
  const float* pz  = (const float*)d_in[2];
  const int*   tri = (const int*)d_in[3];
  const float* Vx  = (const float*)d_in[6];   // [N1][T]
  const float* Vxy = (const float*)d_in[7];   // [N1+N2][T]
  float* out = (float*)d_out;

  float* ws    = (float*)d_ws;
  float* PT    = ws + OFF_PT;
  float* dyzT  = ws + OFF_DYZT;    // dyT, then reused as dzT
  float* cy    = ws + OFF_CY;
  float* cz    = ws + OFF_CZ;
  float* vol   = ws + OFF_VOL;
  float* volc  = ws + OFF_VOLC;
  float* aArr  = ws + OFF_A;
  float* fy    = ws + OFF_FY;
  float* fz    = ws + OFF_FZ;

  // zero atomic-accumulated region: cy + cz + vol + volc (contiguous)
  hipMemsetAsync(cy, 0, (size_t)(128000 + 160000 + 33) * sizeof(float), stream);

  k_init  <<<NPREP + 79, 256, 0, stream>>>(x, y, pz, tri, PT, volc);
  k_dy_vol<<<1250,       256, 0, stream>>>(PT, tri, dyzT, vol);
  k_gemm  <<<dim3(25, 32), 256, 0, stream>>>(dyzT, Vx, cy, N1n);
  k_factor<<<1, 1024, 0, stream>>>(cy, N1n, vol, volc, aArr, fy, 1);
  k_dz    <<<1250,       256, 0, stream>>>(PT, tri, cy, fy, dyzT);
  k_gemm  <<<dim3(25, 40), 256, 0, stream>>>(dyzT, Vxy, cz, NXn);
  k_factor<<<1, 1024, 0, stream>>>(cz, NXn, vol, volc, aArr, fz, 0);
  k_out   <<<1750,       256, 0, stream>>>(x, y, cy, cz, fy, fz, out);
}